// Round 5
// baseline (686.589 us; speedup 1.0000x reference)
//
#include <hip/hip_runtime.h>
#include <hip/hip_bf16.h>

#define RELS 8
typedef unsigned int uint;
typedef unsigned short ushort;
typedef __attribute__((ext_vector_type(8))) short short8;
typedef __attribute__((ext_vector_type(4))) float f32x4;

__device__ __forceinline__ float bf2f(ushort h) { return __uint_as_float(((uint)h) << 16); }
__device__ __forceinline__ ushort f2bf(float f) {
    uint u = __float_as_uint(f);
    u += 0x7fffu + ((u >> 16) & 1u);
    return (ushort)(u >> 16);
}

// ================= CSR build =================
__global__ void count_k(const int* __restrict__ dst, const int* __restrict__ et,
                        int* __restrict__ cnt, int E) {
    int e = blockIdx.x * blockDim.x + threadIdx.x;
    if (e < E) atomicAdd(&cnt[dst[e] * RELS + et[e]], 1);
}

__global__ __launch_bounds__(256) void scan1_k(const int* __restrict__ in,
                                               int* __restrict__ outp,
                                               int* __restrict__ bsum, int n) {
    __shared__ int sh[256];
    const int t = threadIdx.x;
    const int base = blockIdx.x * 2048 + t * 8;
    int v[8]; int s = 0;
#pragma unroll
    for (int j = 0; j < 8; ++j) { int idx = base + j; v[j] = (idx < n) ? in[idx] : 0; s += v[j]; }
    sh[t] = s; __syncthreads();
    for (int off = 1; off < 256; off <<= 1) {
        int x = (t >= off) ? sh[t - off] : 0;
        __syncthreads(); sh[t] += x; __syncthreads();
    }
    if (t == 255) bsum[blockIdx.x] = sh[255];
    int run = t ? sh[t - 1] : 0;
#pragma unroll
    for (int j = 0; j < 8; ++j) { int idx = base + j; if (idx < n) outp[idx] = run; run += v[j]; }
}

__global__ __launch_bounds__(256) void scan2_k(int* __restrict__ a, int n) {
    __shared__ int sh[256];
    const int t = threadIdx.x;
    const int base = t * 8;
    int v[8]; int s = 0;
#pragma unroll
    for (int j = 0; j < 8; ++j) { int idx = base + j; v[j] = (idx < n) ? a[idx] : 0; s += v[j]; }
    sh[t] = s; __syncthreads();
    for (int off = 1; off < 256; off <<= 1) {
        int x = (t >= off) ? sh[t - off] : 0;
        __syncthreads(); sh[t] += x; __syncthreads();
    }
    int run = t ? sh[t - 1] : 0;
#pragma unroll
    for (int j = 0; j < 8; ++j) { int idx = base + j; if (idx < n) a[idx] = run; run += v[j]; }
}

__global__ void scan3_k(int* __restrict__ outp, const int* __restrict__ bsum, int n) {
    const int base = blockIdx.x * 2048 + threadIdx.x * 8;
    const int add = bsum[blockIdx.x];
#pragma unroll
    for (int j = 0; j < 8; ++j) { int idx = base + j; if (idx < n) outp[idx] += add; }
}

// stores SRC node id (not edge id) -> removes one indirection in the gather hot loop
__global__ void fill_k(const int* __restrict__ dst, const int* __restrict__ et,
                       const int* __restrict__ src,
                       int* __restrict__ offs, int* __restrict__ srcs, int E) {
    int e = blockIdx.x * blockDim.x + threadIdx.x;
    if (e < E) {
        int seg = dst[e] * RELS + et[e];
        int p = atomicAdd(&offs[seg], 1);
        srcs[p] = src[e];
    }
}

// ================= dtype prep =================
__global__ void cvt_bf16_k(const float* __restrict__ in, ushort* __restrict__ out, long long n4) {
    long long i = ((long long)blockIdx.x * blockDim.x + threadIdx.x) * 4;
    if (i >= n4) return;
    float4 v = *(const float4*)(in + i);
    ushort4 o; o.x = f2bf(v.x); o.y = f2bf(v.y); o.z = f2bf(v.z); o.w = f2bf(v.w);
    *(ushort4*)(out + i) = o;
}

// B' fragment layout: Bp[(k>>5)*Co*32 + c*32 + (k&31)] = (k<RK ? W[k][c] : root[k-RK][c])
// -> a wave's b-frag load (16 cols x 32 k) is one contiguous 1KB region.
__global__ void makeBp_k(const float* __restrict__ W, const float* __restrict__ root,
                         ushort* __restrict__ Bp, int Co, int RK, int Kd) {
    const long long tot = (long long)Co * (RK + Kd);
    long long i = (long long)blockIdx.x * blockDim.x + threadIdx.x;
    if (i >= tot) return;
    const int kb = (int)(i / (Co * 32));
    const int rem = (int)(i % (Co * 32));
    const int c = rem >> 5;
    const int k = kb * 32 + (rem & 31);
    float v = (k < RK) ? W[(long long)k * Co + c] : root[(long long)(k - RK) * Co + c];
    Bp[i] = f2bf(v);
}

// ================= fused gather-mean + MFMA GEMM =================
// out[m, 0..2*NJ*16) = sum_{s=0..7} mean_s(X)[m,:] @ W_s + X[m,:] @ root + bias
// A-tile per step staged in XOR-swizzled LDS; B read direct from L2 (Bp layout).
template <int Dk, int NJ, int CO, bool RELU, bool OUTBF>
__global__ __launch_bounds__(256) void fused_rgcn_k(const ushort* __restrict__ X,
                                                    const int* __restrict__ srcs,
                                                    const int* __restrict__ cnt,
                                                    const int* __restrict__ ends,
                                                    const ushort* __restrict__ Bp,
                                                    const float* __restrict__ bias,
                                                    void* __restrict__ outv,
                                                    int M) {
    constexpr int KSL = Dk / 32;   // 16x16x32 k-slices per step
    constexpr int VPL = Dk / 16;   // bf16 per lane in gather (16 lanes per node row)
    __shared__ ushort As[128 * Dk];
    const int tid = threadIdx.x;
    const int l = tid & 63;
    const int wu = __builtin_amdgcn_readfirstlane(tid >> 6);
    const int wr = (wu >> 1) * 64;
    const int wc = (wu & 1) * (NJ * 16);
    const int row0 = blockIdx.x * 128;
    const int sub = l >> 4;        // node-in-batch 0..3
    const int li = l & 15;         // lane-in-node

    f32x4 acc[4][NJ];
#pragma unroll
    for (int i = 0; i < 4; ++i)
#pragma unroll
        for (int j = 0; j < NJ; ++j)
            acc[i][j] = (f32x4){0.f, 0.f, 0.f, 0.f};

#pragma unroll 1
    for (int s = 0; s < 9; ++s) {
        // ---------- produce A tile in LDS ----------
        if (s < 8) {
#pragma unroll 1
            for (int b = 0; b < 8; ++b) {
                const int lrow = wu * 32 + b * 4 + sub;
                const int node = row0 + lrow;
                int c = 0; const int* sp = srcs;
                if (node < M) {
                    const int seg = node * RELS + s;
                    c = cnt[seg];
                    sp = srcs + (ends[seg] - c);
                }
                float ar[VPL];
#pragma unroll
                for (int e = 0; e < VPL; ++e) ar[e] = 0.f;
                for (int i = 0; ; ++i) {
                    if (!__any(i < c)) break;
                    if (i < c) {
                        const ushort* row = X + (long long)sp[i] * Dk + li * VPL;
                        short8 v0 = *(const short8*)row;
#pragma unroll
                        for (int e = 0; e < 8; ++e) ar[e] += bf2f((ushort)v0[e]);
                        if constexpr (VPL == 16) {
                            short8 v1 = *(const short8*)(row + 8);
#pragma unroll
                            for (int e = 0; e < 8; ++e) ar[8 + e] += bf2f((ushort)v1[e]);
                        }
                    }
                }
                if (node < M) {
                    const float scv = 1.f / fmaxf((float)c, 1.f);
                    const uint sw = ((uint)(lrow & 7)) << 4;
                    const uint base = (uint)(lrow * (Dk * 2) + li * (VPL * 2));
                    short8 p0;
#pragma unroll
                    for (int e = 0; e < 8; ++e) p0[e] = (short)f2bf(ar[e] * scv);
                    *(short8*)((char*)As + (base ^ sw)) = p0;
                    if constexpr (VPL == 16) {
                        short8 p1;
#pragma unroll
                        for (int e = 0; e < 8; ++e) p1[e] = (short)f2bf(ar[8 + e] * scv);
                        *(short8*)((char*)As + ((base + 16) ^ sw)) = p1;
                    }
                }
            }
        } else {
            // root step: copy X rows (no mean)
#pragma unroll 1
            for (int b = 0; b < 8; ++b) {
                const int lrow = wu * 32 + b * 4 + sub;
                const int node = row0 + lrow;
                if (node < M) {
                    const ushort* row = X + (long long)node * Dk + li * VPL;
                    const uint sw = ((uint)(lrow & 7)) << 4;
                    const uint base = (uint)(lrow * (Dk * 2) + li * (VPL * 2));
                    *(short8*)((char*)As + (base ^ sw)) = *(const short8*)row;
                    if constexpr (VPL == 16)
                        *(short8*)((char*)As + ((base + 16) ^ sw)) = *(const short8*)(row + 8);
                }
            }
        }
        __syncthreads();
        // ---------- MFMA against Bp (direct from L2) ----------
        const int kb0 = s * KSL;
#pragma unroll
        for (int kk = 0; kk < KSL; ++kk) {
            short8 afr[4];
#pragma unroll
            for (int i = 0; i < 4; ++i) {
                const int r = wr + i * 16 + (l & 15);
                const uint byte = ((uint)(r * (Dk * 2) + kk * 64 + ((l >> 4) * 16)))
                                  ^ (((uint)(r & 7)) << 4);
                afr[i] = *(const short8*)((const char*)As + byte);
            }
            short8 bfr[NJ];
#pragma unroll
            for (int j = 0; j < NJ; ++j) {
                const int cidx = wc + j * 16 + (l & 15);
                bfr[j] = *(const short8*)(Bp + ((long long)(kb0 + kk) * CO + cidx) * 32 + (l >> 4) * 8);
            }
#pragma unroll
            for (int i = 0; i < 4; ++i)
#pragma unroll
                for (int j = 0; j < NJ; ++j)
                    acc[i][j] = __builtin_amdgcn_mfma_f32_16x16x32_bf16(afr[i], bfr[j], acc[i][j], 0, 0, 0);
        }
        __syncthreads();
    }

    // ---------- epilogue: C/D map col=lane&15, row=(lane>>4)*4+q ----------
    float bj[NJ];
#pragma unroll
    for (int j = 0; j < NJ; ++j) bj[j] = bias[wc + j * 16 + (l & 15)];
#pragma unroll
    for (int i = 0; i < 4; ++i) {
#pragma unroll
        for (int q = 0; q < 4; ++q) {
            const int row = row0 + wr + i * 16 + (l >> 4) * 4 + q;
            if (row >= M) continue;
#pragma unroll
            for (int j = 0; j < NJ; ++j) {
                const int col = wc + j * 16 + (l & 15);
                float v = acc[i][j][q] + bj[j];
                if (RELU) v = fmaxf(v, 0.0f);
                if (OUTBF) ((ushort*)outv)[(long long)row * CO + col] = f2bf(v);
                else       ((float*)outv)[(long long)row * CO + col] = v;
            }
        }
    }
}

// ================= launcher =================
extern "C" void kernel_launch(void* const* d_in, const int* in_sizes, int n_in,
                              void* d_out, int out_size, void* d_ws, size_t ws_size,
                              hipStream_t stream) {
    const float* x     = (const float*)d_in[0];
    const int*   ei    = (const int*)d_in[1];
    const int*   et    = (const int*)d_in[2];
    const float* W1    = (const float*)d_in[3];
    const float* root1 = (const float*)d_in[4];
    const float* b1    = (const float*)d_in[5];
    const float* W2    = (const float*)d_in[6];
    const float* root2 = (const float*)d_in[7];
    const float* b2    = (const float*)d_in[8];

    const int N = in_sizes[0] / 128;
    const int E = in_sizes[2];
    const int* src = ei;
    const int* dst = ei + E;
    const int NR = N * RELS;

    // workspace (bf16): h1b[N*256] | xb[N*128] | Bp1[1152*256] | Bp2[2304*128]
    // then ints: cnt[NR] | offs[NR] | srcs[E] | bsum[4096]
    ushort* h1b = (ushort*)d_ws;
    ushort* xb  = h1b + (size_t)N * 256;
    ushort* Bp1 = xb + (size_t)N * 128;
    ushort* Bp2 = Bp1 + (size_t)1152 * 256;
    int* cnt  = (int*)(Bp2 + (size_t)2304 * 128);
    int* offs = cnt + NR;
    int* srcs = offs + NR;
    int* bsum = srcs + E;
    size_t need = ((size_t)N * 384 + 589824) * 2 + ((size_t)2 * NR + E + 4096) * 4;
    if (need > ws_size) return;

    // ---- dtype prep ----
    {
        long long n4 = (long long)N * 128;
        cvt_bf16_k<<<(int)((n4 / 4 + 255) / 256), 256, 0, stream>>>(x, xb, n4);
    }
    makeBp_k<<<(1152 * 256 + 255) / 256, 256, 0, stream>>>(W1, root1, Bp1, 256, 1024, 128);
    makeBp_k<<<(2304 * 128 + 255) / 256, 256, 0, stream>>>(W2, root2, Bp2, 128, 2048, 256);

    // ---- CSR build ----
    hipMemsetAsync(cnt, 0, (size_t)NR * sizeof(int), stream);
    count_k<<<(E + 255) / 256, 256, 0, stream>>>(dst, et, cnt, E);
    const int nb1 = (NR + 2047) / 2048;
    scan1_k<<<nb1, 256, 0, stream>>>(cnt, offs, bsum, NR);
    scan2_k<<<1, 256, 0, stream>>>(bsum, nb1);
    scan3_k<<<nb1, 256, 0, stream>>>(offs, bsum, NR);
    fill_k<<<(E + 255) / 256, 256, 0, stream>>>(dst, et, src, offs, srcs, E);
    // offs now holds segment ENDS; start = end - cnt

    const int nblk = (N + 127) / 128;

    // ---- layer 1: h1b = relu([mean_r(x)|x] @ [W1;root1] + b1), bf16 out ----
    fused_rgcn_k<128, 8, 256, true, true><<<nblk, 256, 0, stream>>>(
        xb, srcs, cnt, offs, Bp1, b1, h1b, N);

    // ---- layer 2: out = [mean_r(h1)|h1] @ [W2;root2] + b2, fp32 out ----
    fused_rgcn_k<256, 4, 128, false, false><<<nblk, 256, 0, stream>>>(
        h1b, srcs, cnt, offs, Bp2, b2, d_out, N);
}

// Round 6
// 572.307 us; speedup vs baseline: 1.1997x; 1.1997x over previous
//
#include <hip/hip_runtime.h>
#include <hip/hip_bf16.h>

#define RELS 8
typedef unsigned int uint;
typedef unsigned short ushort;
typedef __attribute__((ext_vector_type(8))) short short8;
typedef __attribute__((ext_vector_type(4))) float f32x4;

__device__ __forceinline__ float bf2f(ushort h) { return __uint_as_float(((uint)h) << 16); }
__device__ __forceinline__ ushort f2bf(float f) {
    uint u = __float_as_uint(f);
    u += 0x7fffu + ((u >> 16) & 1u);
    return (ushort)(u >> 16);
}

// ================= CSR build =================
__global__ void count_k(const int* __restrict__ dst, const int* __restrict__ et,
                        int* __restrict__ cnt, int E) {
    int e = blockIdx.x * blockDim.x + threadIdx.x;
    if (e < E) atomicAdd(&cnt[dst[e] * RELS + et[e]], 1);
}

__global__ __launch_bounds__(256) void scan1_k(const int* __restrict__ in,
                                               int* __restrict__ outp,
                                               int* __restrict__ bsum, int n) {
    __shared__ int sh[256];
    const int t = threadIdx.x;
    const int base = blockIdx.x * 2048 + t * 8;
    int v[8]; int s = 0;
#pragma unroll
    for (int j = 0; j < 8; ++j) { int idx = base + j; v[j] = (idx < n) ? in[idx] : 0; s += v[j]; }
    sh[t] = s; __syncthreads();
    for (int off = 1; off < 256; off <<= 1) {
        int x = (t >= off) ? sh[t - off] : 0;
        __syncthreads(); sh[t] += x; __syncthreads();
    }
    if (t == 255) bsum[blockIdx.x] = sh[255];
    int run = t ? sh[t - 1] : 0;
#pragma unroll
    for (int j = 0; j < 8; ++j) { int idx = base + j; if (idx < n) outp[idx] = run; run += v[j]; }
}

__global__ __launch_bounds__(256) void scan2_k(int* __restrict__ a, int n) {
    __shared__ int sh[256];
    const int t = threadIdx.x;
    const int base = t * 8;
    int v[8]; int s = 0;
#pragma unroll
    for (int j = 0; j < 8; ++j) { int idx = base + j; v[j] = (idx < n) ? a[idx] : 0; s += v[j]; }
    sh[t] = s; __syncthreads();
    for (int off = 1; off < 256; off <<= 1) {
        int x = (t >= off) ? sh[t - off] : 0;
        __syncthreads(); sh[t] += x; __syncthreads();
    }
    int run = t ? sh[t - 1] : 0;
#pragma unroll
    for (int j = 0; j < 8; ++j) { int idx = base + j; if (idx < n) a[idx] = run; run += v[j]; }
}

__global__ void scan3_k(int* __restrict__ outp, const int* __restrict__ bsum, int n) {
    const int base = blockIdx.x * 2048 + threadIdx.x * 8;
    const int add = bsum[blockIdx.x];
#pragma unroll
    for (int j = 0; j < 8; ++j) { int idx = base + j; if (idx < n) outp[idx] += add; }
}

// stores SRC node id (not edge id) -> removes one indirection in the gather hot loop
__global__ void fill_k(const int* __restrict__ dst, const int* __restrict__ et,
                       const int* __restrict__ src,
                       int* __restrict__ offs, int* __restrict__ srcs, int E) {
    int e = blockIdx.x * blockDim.x + threadIdx.x;
    if (e < E) {
        int seg = dst[e] * RELS + et[e];
        int p = atomicAdd(&offs[seg], 1);
        srcs[p] = src[e];
    }
}

// ================= dtype prep =================
__global__ void cvt_bf16_k(const float* __restrict__ in, ushort* __restrict__ out, long long n4) {
    long long i = ((long long)blockIdx.x * blockDim.x + threadIdx.x) * 4;
    if (i >= n4) return;
    float4 v = *(const float4*)(in + i);
    ushort4 o; o.x = f2bf(v.x); o.y = f2bf(v.y); o.z = f2bf(v.z); o.w = f2bf(v.w);
    *(ushort4*)(out + i) = o;
}

// B' fragment layout: Bp[(k>>5)*Co*32 + c*32 + (k&31)] = (k<RK ? W[k][c] : root[k-RK][c])
// -> a wave's b-frag load (16 cols x 32 k) is one contiguous 1KB region.
__global__ void makeBp_k(const float* __restrict__ W, const float* __restrict__ root,
                         ushort* __restrict__ Bp, int Co, int RK, int Kd) {
    const long long tot = (long long)Co * (RK + Kd);
    long long i = (long long)blockIdx.x * blockDim.x + threadIdx.x;
    if (i >= tot) return;
    const int kb = (int)(i / (Co * 32));
    const int rem = (int)(i % (Co * 32));
    const int c = rem >> 5;
    const int k = kb * 32 + (rem & 31);
    float v = (k < RK) ? W[(long long)k * Co + c] : root[(long long)(k - RK) * Co + c];
    Bp[i] = f2bf(v);
}

// ================= fused gather-mean + MFMA GEMM (M-tile = 64) =================
// out[m, :] = sum_{s=0..7} mean_s(X)[m,:] @ W_s + X[m,:] @ root + bias
// 4 waves split the COLUMN dim (wave w -> cols [w*NJ*16, (w+1)*NJ*16)); all waves
// share the 64-row A tile in XOR-swizzled LDS; B read direct from L2 (Bp layout).
template <int Dk, int NJ, int CO, bool RELU, bool OUTBF>
__global__ __launch_bounds__(256) void fused_rgcn_k(const ushort* __restrict__ X,
                                                    const int* __restrict__ srcs,
                                                    const int* __restrict__ cnt,
                                                    const int* __restrict__ ends,
                                                    const ushort* __restrict__ Bp,
                                                    const float* __restrict__ bias,
                                                    void* __restrict__ outv,
                                                    int M) {
    constexpr int KSL = Dk / 32;   // 16x16x32 k-slices per step
    constexpr int VPL = Dk / 16;   // bf16 per lane in gather (16 lanes per node row)
    __shared__ ushort As[64 * Dk];
    const int tid = threadIdx.x;
    const int l = tid & 63;
    const int wu = __builtin_amdgcn_readfirstlane(tid >> 6);
    const int wc = wu * (NJ * 16);
    const int row0 = blockIdx.x * 64;
    const int sub = l >> 4;        // node-in-batch 0..3
    const int li = l & 15;         // lane-in-node

    f32x4 acc[4][NJ];
#pragma unroll
    for (int i = 0; i < 4; ++i)
#pragma unroll
        for (int j = 0; j < NJ; ++j)
            acc[i][j] = (f32x4){0.f, 0.f, 0.f, 0.f};

#pragma unroll 1
    for (int s = 0; s < 9; ++s) {
        // ---------- produce A tile in LDS (each wave owns 16 rows) ----------
        if (s < 8) {
#pragma unroll 1
            for (int b = 0; b < 4; ++b) {
                const int lrow = wu * 16 + b * 4 + sub;
                const int node = row0 + lrow;
                int c = 0; const int* sp = srcs;
                if (node < M) {
                    const int seg = node * RELS + s;
                    c = cnt[seg];
                    sp = srcs + (ends[seg] - c);
                }
                float ar[VPL];
#pragma unroll
                for (int e = 0; e < VPL; ++e) ar[e] = 0.f;
                // 2-deep unrolled gather for ILP
                for (int i = 0; __any(i < c); i += 2) {
                    if (i < c) {
                        const ushort* row = X + (long long)sp[i] * Dk + li * VPL;
                        short8 v0 = *(const short8*)row;
                        short8 v1;
                        if constexpr (VPL == 16) v1 = *(const short8*)(row + 8);
#pragma unroll
                        for (int e = 0; e < 8; ++e) ar[e] += bf2f((ushort)v0[e]);
                        if constexpr (VPL == 16) {
#pragma unroll
                            for (int e = 0; e < 8; ++e) ar[8 + e] += bf2f((ushort)v1[e]);
                        }
                    }
                    if (i + 1 < c) {
                        const ushort* row = X + (long long)sp[i + 1] * Dk + li * VPL;
                        short8 v0 = *(const short8*)row;
                        short8 v1;
                        if constexpr (VPL == 16) v1 = *(const short8*)(row + 8);
#pragma unroll
                        for (int e = 0; e < 8; ++e) ar[e] += bf2f((ushort)v0[e]);
                        if constexpr (VPL == 16) {
#pragma unroll
                            for (int e = 0; e < 8; ++e) ar[8 + e] += bf2f((ushort)v1[e]);
                        }
                    }
                }
                if (node < M) {
                    const float scv = 1.f / fmaxf((float)c, 1.f);
                    const uint sw = ((uint)(lrow & 7)) << 4;
                    const uint base = (uint)(lrow * (Dk * 2) + li * (VPL * 2));
                    short8 p0;
#pragma unroll
                    for (int e = 0; e < 8; ++e) p0[e] = (short)f2bf(ar[e] * scv);
                    *(short8*)((char*)As + (base ^ sw)) = p0;
                    if constexpr (VPL == 16) {
                        short8 p1;
#pragma unroll
                        for (int e = 0; e < 8; ++e) p1[e] = (short)f2bf(ar[8 + e] * scv);
                        *(short8*)((char*)As + ((base + 16) ^ sw)) = p1;
                    }
                }
            }
        } else {
            // root step: copy X rows (no mean)
#pragma unroll 1
            for (int b = 0; b < 4; ++b) {
                const int lrow = wu * 16 + b * 4 + sub;
                const int node = row0 + lrow;
                if (node < M) {
                    const ushort* row = X + (long long)node * Dk + li * VPL;
                    const uint sw = ((uint)(lrow & 7)) << 4;
                    const uint base = (uint)(lrow * (Dk * 2) + li * (VPL * 2));
                    *(short8*)((char*)As + (base ^ sw)) = *(const short8*)row;
                    if constexpr (VPL == 16)
                        *(short8*)((char*)As + ((base + 16) ^ sw)) = *(const short8*)(row + 8);
                }
            }
        }
        __syncthreads();
        // ---------- MFMA against Bp (direct from L2) ----------
        const int kb0 = s * KSL;
#pragma unroll
        for (int kk = 0; kk < KSL; ++kk) {
            short8 afr[4];
#pragma unroll
            for (int i = 0; i < 4; ++i) {
                const int r = i * 16 + (l & 15);
                const uint byte = ((uint)(r * (Dk * 2) + kk * 64 + ((l >> 4) * 16)))
                                  ^ (((uint)(r & 7)) << 4);
                afr[i] = *(const short8*)((const char*)As + byte);
            }
            short8 bfr[NJ];
#pragma unroll
            for (int j = 0; j < NJ; ++j) {
                const int cidx = wc + j * 16 + (l & 15);
                bfr[j] = *(const short8*)(Bp + ((long long)(kb0 + kk) * CO + cidx) * 32 + (l >> 4) * 8);
            }
#pragma unroll
            for (int i = 0; i < 4; ++i)
#pragma unroll
                for (int j = 0; j < NJ; ++j)
                    acc[i][j] = __builtin_amdgcn_mfma_f32_16x16x32_bf16(afr[i], bfr[j], acc[i][j], 0, 0, 0);
        }
        __syncthreads();
    }

    // ---------- epilogue: C/D map col=lane&15, row=(lane>>4)*4+q ----------
    float bj[NJ];
#pragma unroll
    for (int j = 0; j < NJ; ++j) bj[j] = bias[wc + j * 16 + (l & 15)];
#pragma unroll
    for (int i = 0; i < 4; ++i) {
#pragma unroll
        for (int q = 0; q < 4; ++q) {
            const int row = row0 + i * 16 + (l >> 4) * 4 + q;
            if (row >= M) continue;
#pragma unroll
            for (int j = 0; j < NJ; ++j) {
                const int col = wc + j * 16 + (l & 15);
                float v = acc[i][j][q] + bj[j];
                if (RELU) v = fmaxf(v, 0.0f);
                if (OUTBF) ((ushort*)outv)[(long long)row * CO + col] = f2bf(v);
                else       ((float*)outv)[(long long)row * CO + col] = v;
            }
        }
    }
}

// ================= launcher =================
extern "C" void kernel_launch(void* const* d_in, const int* in_sizes, int n_in,
                              void* d_out, int out_size, void* d_ws, size_t ws_size,
                              hipStream_t stream) {
    const float* x     = (const float*)d_in[0];
    const int*   ei    = (const int*)d_in[1];
    const int*   et    = (const int*)d_in[2];
    const float* W1    = (const float*)d_in[3];
    const float* root1 = (const float*)d_in[4];
    const float* b1    = (const float*)d_in[5];
    const float* W2    = (const float*)d_in[6];
    const float* root2 = (const float*)d_in[7];
    const float* b2    = (const float*)d_in[8];

    const int N = in_sizes[0] / 128;
    const int E = in_sizes[2];
    const int* src = ei;
    const int* dst = ei + E;
    const int NR = N * RELS;

    // workspace (bf16): h1b[N*256] | xb[N*128] | Bp1[1152*256] | Bp2[2304*128]
    // then ints: cnt[NR] | offs[NR] | srcs[E] | bsum[4096]
    ushort* h1b = (ushort*)d_ws;
    ushort* xb  = h1b + (size_t)N * 256;
    ushort* Bp1 = xb + (size_t)N * 128;
    ushort* Bp2 = Bp1 + (size_t)1152 * 256;
    int* cnt  = (int*)(Bp2 + (size_t)2304 * 128);
    int* offs = cnt + NR;
    int* srcs = offs + NR;
    int* bsum = srcs + E;
    size_t need = ((size_t)N * 384 + 589824) * 2 + ((size_t)2 * NR + E + 4096) * 4;
    if (need > ws_size) return;

    // ---- dtype prep ----
    {
        long long n4 = (long long)N * 128;
        cvt_bf16_k<<<(int)((n4 / 4 + 255) / 256), 256, 0, stream>>>(x, xb, n4);
    }
    makeBp_k<<<(1152 * 256 + 255) / 256, 256, 0, stream>>>(W1, root1, Bp1, 256, 1024, 128);
    makeBp_k<<<(2304 * 128 + 255) / 256, 256, 0, stream>>>(W2, root2, Bp2, 128, 2048, 256);

    // ---- CSR build ----
    hipMemsetAsync(cnt, 0, (size_t)NR * sizeof(int), stream);
    count_k<<<(E + 255) / 256, 256, 0, stream>>>(dst, et, cnt, E);
    const int nb1 = (NR + 2047) / 2048;
    scan1_k<<<nb1, 256, 0, stream>>>(cnt, offs, bsum, NR);
    scan2_k<<<1, 256, 0, stream>>>(bsum, nb1);
    scan3_k<<<nb1, 256, 0, stream>>>(offs, bsum, NR);
    fill_k<<<(E + 255) / 256, 256, 0, stream>>>(dst, et, src, offs, srcs, E);
    // offs now holds segment ENDS; start = end - cnt

    const int nblk = (N + 63) / 64;

    // ---- layer 1: h1b = relu([mean_r(x)|x] @ [W1;root1] + b1), bf16 out ----
    fused_rgcn_k<128, 4, 256, true, true><<<nblk, 256, 0, stream>>>(
        xb, srcs, cnt, offs, Bp1, b1, h1b, N);

    // ---- layer 2: out = [mean_r(h1)|h1] @ [W2;root2] + b2, fp32 out ----
    fused_rgcn_k<256, 2, 128, false, false><<<nblk, 256, 0, stream>>>(
        h1b, srcs, cnt, offs, Bp2, b2, d_out, N);
}

// Round 7
// 452.963 us; speedup vs baseline: 1.5158x; 1.2635x over previous
//
#include <hip/hip_runtime.h>
#include <hip/hip_bf16.h>

#define RELS 8
typedef unsigned int uint;
typedef unsigned short ushort;
typedef __attribute__((ext_vector_type(8))) short short8;
typedef __attribute__((ext_vector_type(4))) float f32x4;
typedef __attribute__((ext_vector_type(2))) float f32x2;

__device__ __forceinline__ float bf2f(ushort h) { return __uint_as_float(((uint)h) << 16); }
__device__ __forceinline__ ushort f2bf(float f) {
    uint u = __float_as_uint(f);
    u += 0x7fffu + ((u >> 16) & 1u);
    return (ushort)(u >> 16);
}

// ================= CSR build =================
__global__ void count_k(const int* __restrict__ dst, const int* __restrict__ et,
                        int* __restrict__ cnt, int E) {
    int e = blockIdx.x * blockDim.x + threadIdx.x;
    if (e < E) atomicAdd(&cnt[dst[e] * RELS + et[e]], 1);
}

__global__ __launch_bounds__(256) void scan1_k(const int* __restrict__ in,
                                               int* __restrict__ outp,
                                               int* __restrict__ bsum, int n) {
    __shared__ int sh[256];
    const int t = threadIdx.x;
    const int base = blockIdx.x * 2048 + t * 8;
    int v[8]; int s = 0;
#pragma unroll
    for (int j = 0; j < 8; ++j) { int idx = base + j; v[j] = (idx < n) ? in[idx] : 0; s += v[j]; }
    sh[t] = s; __syncthreads();
    for (int off = 1; off < 256; off <<= 1) {
        int x = (t >= off) ? sh[t - off] : 0;
        __syncthreads(); sh[t] += x; __syncthreads();
    }
    if (t == 255) bsum[blockIdx.x] = sh[255];
    int run = t ? sh[t - 1] : 0;
#pragma unroll
    for (int j = 0; j < 8; ++j) { int idx = base + j; if (idx < n) outp[idx] = run; run += v[j]; }
}

__global__ __launch_bounds__(256) void scan2_k(int* __restrict__ a, int n) {
    __shared__ int sh[256];
    const int t = threadIdx.x;
    const int base = t * 8;
    int v[8]; int s = 0;
#pragma unroll
    for (int j = 0; j < 8; ++j) { int idx = base + j; v[j] = (idx < n) ? a[idx] : 0; s += v[j]; }
    sh[t] = s; __syncthreads();
    for (int off = 1; off < 256; off <<= 1) {
        int x = (t >= off) ? sh[t - off] : 0;
        __syncthreads(); sh[t] += x; __syncthreads();
    }
    int run = t ? sh[t - 1] : 0;
#pragma unroll
    for (int j = 0; j < 8; ++j) { int idx = base + j; if (idx < n) a[idx] = run; run += v[j]; }
}

__global__ void scan3_k(int* __restrict__ outp, const int* __restrict__ bsum, int n) {
    const int base = blockIdx.x * 2048 + threadIdx.x * 8;
    const int add = bsum[blockIdx.x];
#pragma unroll
    for (int j = 0; j < 8; ++j) { int idx = base + j; if (idx < n) outp[idx] += add; }
}

// stores SRC node id (not edge id) -> removes one indirection in the gather hot loop
__global__ void fill_k(const int* __restrict__ dst, const int* __restrict__ et,
                       const int* __restrict__ src,
                       int* __restrict__ offs, int* __restrict__ srcs, int E) {
    int e = blockIdx.x * blockDim.x + threadIdx.x;
    if (e < E) {
        int seg = dst[e] * RELS + et[e];
        int p = atomicAdd(&offs[seg], 1);
        srcs[p] = src[e];
    }
}

// ================= dtype prep =================
__global__ void cvt_bf16_k(const float* __restrict__ in, ushort* __restrict__ out, long long n4) {
    long long i = ((long long)blockIdx.x * blockDim.x + threadIdx.x) * 4;
    if (i >= n4) return;
    float4 v = *(const float4*)(in + i);
    ushort4 o; o.x = f2bf(v.x); o.y = f2bf(v.y); o.z = f2bf(v.z); o.w = f2bf(v.w);
    *(ushort4*)(out + i) = o;
}

// B' fragment layout: Bp[(k>>5)*Co*32 + c*32 + (k&31)] = (k<RK ? W[k][c] : root[k-RK][c])
__global__ void makeBp_k(const float* __restrict__ W, const float* __restrict__ root,
                         ushort* __restrict__ Bp, int Co, int RK, int Kd) {
    const long long tot = (long long)Co * (RK + Kd);
    long long i = (long long)blockIdx.x * blockDim.x + threadIdx.x;
    if (i >= tot) return;
    const int kb = (int)(i / (Co * 32));
    const int rem = (int)(i % (Co * 32));
    const int c = rem >> 5;
    const int k = kb * 32 + (rem & 31);
    float v = (k < RK) ? W[(long long)k * Co + c] : root[(long long)(k - RK) * Co + c];
    Bp[i] = f2bf(v);
}

// ================= fused gather-mean + MFMA GEMM (M-tile = 32, 8 waves) =================
// out[m, :] = sum_{s=0..7} mean_s(X)[m,:] @ W_s + X[m,:] @ root + bias
// 512 threads: 32 16-lane groups each own ONE (node, rel) segment per step;
// 8 waves split the COLUMN dim (wave w -> cols [w*NJ*16, ...)).
// A-tile XOR-swizzled in LDS; B read direct from L2 (Bp frag layout).
template <int Dk, int NJ, int CO, bool RELU, bool OUTBF>
__global__ __launch_bounds__(512, 8) void fused_rgcn_k(const ushort* __restrict__ X,
                                                       const int* __restrict__ srcs,
                                                       const int* __restrict__ cnt,
                                                       const int* __restrict__ ends,
                                                       const ushort* __restrict__ Bp,
                                                       const float* __restrict__ bias,
                                                       void* __restrict__ outv,
                                                       int M) {
    constexpr int KSL = Dk / 32;    // 16x16x32 k-slices per step
    constexpr int VPL = Dk / 16;    // bf16 per lane in gather (16 lanes per node row)
    constexpr int NDW = VPL / 2;    // dwords per lane (4 or 8)
    __shared__ ushort As[32 * Dk];
    const int tid = threadIdx.x;
    const int l = tid & 63;
    const int wu = __builtin_amdgcn_readfirstlane(tid >> 6);  // 0..7
    const int wc = wu * (NJ * 16);
    const int row0 = blockIdx.x * 32;
    const int lrow = tid >> 4;      // group id 0..31 == local row
    const int li = tid & 15;        // lane-in-node

    const ushort* Xli = X + li * VPL;   // per-lane column base

    f32x4 acc[2][NJ];
#pragma unroll
    for (int i = 0; i < 2; ++i)
#pragma unroll
        for (int j = 0; j < NJ; ++j)
            acc[i][j] = (f32x4){0.f, 0.f, 0.f, 0.f};

#pragma unroll 1
    for (int s = 0; s < 9; ++s) {
        const int node = row0 + lrow;
        const uint sw = ((uint)(lrow & 7)) << 4;
        const uint wbase = (uint)(lrow * (Dk * 2) + li * (VPL * 2));
        // ---------- produce A tile in LDS (one segment per 16-lane group) ----------
        if (s < 8) {
            int c = 0; const int* sp = srcs;
            if (node < M) {
                const int seg = node * RELS + s;
                c = cnt[seg];
                sp = srcs + (ends[seg] - c);
            }
            f32x2 ar[NDW];
#pragma unroll
            for (int p = 0; p < NDW; ++p) ar[p] = (f32x2){0.f, 0.f};
            for (int i = 0; __any(i < c); i += 2) {
                if (i < c) {
                    const ushort* row = Xli + (uint)sp[i] * (uint)Dk;
                    uint4 v0 = *(const uint4*)row;
                    uint4 v1;
                    if constexpr (NDW == 8) v1 = *(const uint4*)(row + 8);
#pragma unroll
                    for (int p = 0; p < 4; ++p) {
                        uint u = (&v0.x)[p];
                        f32x2 t; t.x = __uint_as_float(u << 16); t.y = __uint_as_float(u & 0xffff0000u);
                        ar[p] += t;
                    }
                    if constexpr (NDW == 8) {
#pragma unroll
                        for (int p = 0; p < 4; ++p) {
                            uint u = (&v1.x)[p];
                            f32x2 t; t.x = __uint_as_float(u << 16); t.y = __uint_as_float(u & 0xffff0000u);
                            ar[4 + p] += t;
                        }
                    }
                }
                if (i + 1 < c) {
                    const ushort* row = Xli + (uint)sp[i + 1] * (uint)Dk;
                    uint4 v0 = *(const uint4*)row;
                    uint4 v1;
                    if constexpr (NDW == 8) v1 = *(const uint4*)(row + 8);
#pragma unroll
                    for (int p = 0; p < 4; ++p) {
                        uint u = (&v0.x)[p];
                        f32x2 t; t.x = __uint_as_float(u << 16); t.y = __uint_as_float(u & 0xffff0000u);
                        ar[p] += t;
                    }
                    if constexpr (NDW == 8) {
#pragma unroll
                        for (int p = 0; p < 4; ++p) {
                            uint u = (&v1.x)[p];
                            f32x2 t; t.x = __uint_as_float(u << 16); t.y = __uint_as_float(u & 0xffff0000u);
                            ar[4 + p] += t;
                        }
                    }
                }
            }
            if (node < M) {
                const float scv = 1.f / fmaxf((float)c, 1.f);
                short8 p0;
#pragma unroll
                for (int e = 0; e < 8; ++e)
                    p0[e] = (short)f2bf(ar[e >> 1][e & 1] * scv);
                *(short8*)((char*)As + (wbase ^ sw)) = p0;
                if constexpr (NDW == 8) {
                    short8 p1;
#pragma unroll
                    for (int e = 0; e < 8; ++e)
                        p1[e] = (short)f2bf(ar[4 + (e >> 1)][e & 1] * scv);
                    *(short8*)((char*)As + ((wbase + 16) ^ sw)) = p1;
                }
            }
        } else {
            // root step: copy X rows (no mean)
            if (node < M) {
                const ushort* row = Xli + (uint)node * (uint)Dk;
                *(short8*)((char*)As + (wbase ^ sw)) = *(const short8*)row;
                if constexpr (NDW == 8)
                    *(short8*)((char*)As + ((wbase + 16) ^ sw)) = *(const short8*)(row + 8);
            }
        }
        __syncthreads();
        // ---------- MFMA against Bp (direct from L2) ----------
        const int kb0 = s * KSL;
#pragma unroll
        for (int kk = 0; kk < KSL; ++kk) {
            short8 afr[2];
#pragma unroll
            for (int i = 0; i < 2; ++i) {
                const int r = i * 16 + (l & 15);
                const uint byte = ((uint)(r * (Dk * 2) + kk * 64 + ((l >> 4) * 16)))
                                  ^ (((uint)(r & 7)) << 4);
                afr[i] = *(const short8*)((const char*)As + byte);
            }
            short8 bfr[NJ];
#pragma unroll
            for (int j = 0; j < NJ; ++j) {
                const int cidx = wc + j * 16 + (l & 15);
                bfr[j] = *(const short8*)(Bp + ((long long)(kb0 + kk) * CO + cidx) * 32 + (l >> 4) * 8);
            }
#pragma unroll
            for (int i = 0; i < 2; ++i)
#pragma unroll
                for (int j = 0; j < NJ; ++j)
                    acc[i][j] = __builtin_amdgcn_mfma_f32_16x16x32_bf16(afr[i], bfr[j], acc[i][j], 0, 0, 0);
        }
        __syncthreads();
    }

    // ---------- epilogue: C/D map col=lane&15, row=(lane>>4)*4+q ----------
    float bj[NJ];
#pragma unroll
    for (int j = 0; j < NJ; ++j) bj[j] = bias[wc + j * 16 + (l & 15)];
#pragma unroll
    for (int i = 0; i < 2; ++i) {
#pragma unroll
        for (int q = 0; q < 4; ++q) {
            const int row = row0 + i * 16 + (l >> 4) * 4 + q;
            if (row >= M) continue;
#pragma unroll
            for (int j = 0; j < NJ; ++j) {
                const int col = wc + j * 16 + (l & 15);
                float v = acc[i][j][q] + bj[j];
                if (RELU) v = fmaxf(v, 0.0f);
                if (OUTBF) ((ushort*)outv)[(long long)row * CO + col] = f2bf(v);
                else       ((float*)outv)[(long long)row * CO + col] = v;
            }
        }
    }
}

// ================= launcher =================
extern "C" void kernel_launch(void* const* d_in, const int* in_sizes, int n_in,
                              void* d_out, int out_size, void* d_ws, size_t ws_size,
                              hipStream_t stream) {
    const float* x     = (const float*)d_in[0];
    const int*   ei    = (const int*)d_in[1];
    const int*   et    = (const int*)d_in[2];
    const float* W1    = (const float*)d_in[3];
    const float* root1 = (const float*)d_in[4];
    const float* b1    = (const float*)d_in[5];
    const float* W2    = (const float*)d_in[6];
    const float* root2 = (const float*)d_in[7];
    const float* b2    = (const float*)d_in[8];

    const int N = in_sizes[0] / 128;
    const int E = in_sizes[2];
    const int* src = ei;
    const int* dst = ei + E;
    const int NR = N * RELS;

    // workspace (bf16): h1b[N*256] | xb[N*128] | Bp1[1152*256] | Bp2[2304*128]
    // then ints: cnt[NR] | offs[NR] | srcs[E] | bsum[4096]
    ushort* h1b = (ushort*)d_ws;
    ushort* xb  = h1b + (size_t)N * 256;
    ushort* Bp1 = xb + (size_t)N * 128;
    ushort* Bp2 = Bp1 + (size_t)1152 * 256;
    int* cnt  = (int*)(Bp2 + (size_t)2304 * 128);
    int* offs = cnt + NR;
    int* srcs = offs + NR;
    int* bsum = srcs + E;
    size_t need = ((size_t)N * 384 + 589824) * 2 + ((size_t)2 * NR + E + 4096) * 4;
    if (need > ws_size) return;

    // ---- dtype prep ----
    {
        long long n4 = (long long)N * 128;
        cvt_bf16_k<<<(int)((n4 / 4 + 255) / 256), 256, 0, stream>>>(x, xb, n4);
    }
    makeBp_k<<<(1152 * 256 + 255) / 256, 256, 0, stream>>>(W1, root1, Bp1, 256, 1024, 128);
    makeBp_k<<<(2304 * 128 + 255) / 256, 256, 0, stream>>>(W2, root2, Bp2, 128, 2048, 256);

    // ---- CSR build ----
    hipMemsetAsync(cnt, 0, (size_t)NR * sizeof(int), stream);
    count_k<<<(E + 255) / 256, 256, 0, stream>>>(dst, et, cnt, E);
    const int nb1 = (NR + 2047) / 2048;
    scan1_k<<<nb1, 256, 0, stream>>>(cnt, offs, bsum, NR);
    scan2_k<<<1, 256, 0, stream>>>(bsum, nb1);
    scan3_k<<<nb1, 256, 0, stream>>>(offs, bsum, NR);
    fill_k<<<(E + 255) / 256, 256, 0, stream>>>(dst, et, src, offs, srcs, E);
    // offs now holds segment ENDS; start = end - cnt

    const int nblk = (N + 31) / 32;

    // ---- layer 1: h1b = relu([mean_r(x)|x] @ [W1;root1] + b1), bf16 out ----
    fused_rgcn_k<128, 2, 256, true, true><<<nblk, 512, 0, stream>>>(
        xb, srcs, cnt, offs, Bp1, b1, h1b, N);

    // ---- layer 2: out = [mean_r(h1)|h1] @ [W2;root2] + b2, fp32 out ----
    fused_rgcn_k<256, 1, 128, false, false><<<nblk, 512, 0, stream>>>(
        h1b, srcs, cnt, offs, Bp2, b2, d_out, N);
}

// Round 9
// 433.232 us; speedup vs baseline: 1.5848x; 1.0455x over previous
//
#include <hip/hip_runtime.h>
#include <hip/hip_bf16.h>

#define RELS 8
typedef unsigned int uint;
typedef unsigned short ushort;
typedef __attribute__((ext_vector_type(8))) short short8;
typedef __attribute__((ext_vector_type(4))) float f32x4;
typedef __attribute__((ext_vector_type(2))) float f32x2;

__device__ __forceinline__ float bf2f(ushort h) { return __uint_as_float(((uint)h) << 16); }
__device__ __forceinline__ ushort f2bf(float f) {
    uint u = __float_as_uint(f);
    u += 0x7fffu + ((u >> 16) & 1u);
    return (ushort)(u >> 16);
}

// ================= CSR build =================
__global__ void count_k(const int* __restrict__ dst, const int* __restrict__ et,
                        int* __restrict__ cnt, int E) {
    int e = blockIdx.x * blockDim.x + threadIdx.x;
    if (e < E) atomicAdd(&cnt[dst[e] * RELS + et[e]], 1);
}

__global__ __launch_bounds__(256) void scan1_k(const int* __restrict__ in,
                                               int* __restrict__ outp,
                                               int* __restrict__ bsum, int n) {
    __shared__ int sh[256];
    const int t = threadIdx.x;
    const int base = blockIdx.x * 2048 + t * 8;
    int v[8]; int s = 0;
#pragma unroll
    for (int j = 0; j < 8; ++j) { int idx = base + j; v[j] = (idx < n) ? in[idx] : 0; s += v[j]; }
    sh[t] = s; __syncthreads();
    for (int off = 1; off < 256; off <<= 1) {
        int x = (t >= off) ? sh[t - off] : 0;
        __syncthreads(); sh[t] += x; __syncthreads();
    }
    if (t == 255) bsum[blockIdx.x] = sh[255];
    int run = t ? sh[t - 1] : 0;
#pragma unroll
    for (int j = 0; j < 8; ++j) { int idx = base + j; if (idx < n) outp[idx] = run; run += v[j]; }
}

__global__ __launch_bounds__(256) void scan2_k(int* __restrict__ a, int n) {
    __shared__ int sh[256];
    const int t = threadIdx.x;
    const int base = t * 8;
    int v[8]; int s = 0;
#pragma unroll
    for (int j = 0; j < 8; ++j) { int idx = base + j; v[j] = (idx < n) ? a[idx] : 0; s += v[j]; }
    sh[t] = s; __syncthreads();
    for (int off = 1; off < 256; off <<= 1) {
        int x = (t >= off) ? sh[t - off] : 0;
        __syncthreads(); sh[t] += x; __syncthreads();
    }
    int run = t ? sh[t - 1] : 0;
#pragma unroll
    for (int j = 0; j < 8; ++j) { int idx = base + j; if (idx < n) a[idx] = run; run += v[j]; }
}

__global__ void scan3_k(int* __restrict__ outp, const int* __restrict__ bsum, int n) {
    const int base = blockIdx.x * 2048 + threadIdx.x * 8;
    const int add = bsum[blockIdx.x];
#pragma unroll
    for (int j = 0; j < 8; ++j) { int idx = base + j; if (idx < n) outp[idx] += add; }
}

// stores SRC node id (not edge id) -> removes one indirection in the gather hot loop
__global__ void fill_k(const int* __restrict__ dst, const int* __restrict__ et,
                       const int* __restrict__ src,
                       int* __restrict__ offs, int* __restrict__ srcs, int E) {
    int e = blockIdx.x * blockDim.x + threadIdx.x;
    if (e < E) {
        int seg = dst[e] * RELS + et[e];
        int p = atomicAdd(&offs[seg], 1);
        srcs[p] = src[e];
    }
}

// ================= dtype prep =================
__global__ void cvt_bf16_k(const float* __restrict__ in, ushort* __restrict__ out, long long n4) {
    long long i = ((long long)blockIdx.x * blockDim.x + threadIdx.x) * 4;
    if (i >= n4) return;
    float4 v = *(const float4*)(in + i);
    ushort4 o; o.x = f2bf(v.x); o.y = f2bf(v.y); o.z = f2bf(v.z); o.w = f2bf(v.w);
    *(ushort4*)(out + i) = o;
}

// B' fragment layout: Bp[(k>>5)*Co*32 + c*32 + (k&31)] = (k<RK ? W[k][c] : root[k-RK][c])
__global__ void makeBp_k(const float* __restrict__ W, const float* __restrict__ root,
                         ushort* __restrict__ Bp, int Co, int RK, int Kd) {
    const long long tot = (long long)Co * (RK + Kd);
    long long i = (long long)blockIdx.x * blockDim.x + threadIdx.x;
    if (i >= tot) return;
    const int kb = (int)(i / (Co * 32));
    const int rem = (int)(i % (Co * 32));
    const int c = rem >> 5;
    const int k = kb * 32 + (rem & 31);
    float v = (k < RK) ? W[(long long)k * Co + c] : root[(long long)(k - RK) * Co + c];
    Bp[i] = f2bf(v);
}

// ================= fused gather-mean + MFMA GEMM (M-tile = 32, 8 waves) =================
// out[m, :] = sum_{s=0..7} mean_s(X)[m,:] @ W_s + X[m,:] @ root + bias
// 512 threads; GW-lane groups own one node row each (GW*8 bf16 = full Dk row,
// one contiguous uint4/lane load -> clean 64B sectors). 8 waves split columns.
// A-tile XOR-swizzled in LDS; B read direct from L2 (Bp frag layout).
template <int Dk, int GW, int NJ, int CO, bool RELU, bool OUTBF>
__global__ __launch_bounds__(512, 6) void fused_rgcn_k(const ushort* __restrict__ X,
                                                       const int* __restrict__ srcs,
                                                       const int* __restrict__ cnt,
                                                       const int* __restrict__ ends,
                                                       const ushort* __restrict__ Bp,
                                                       const float* __restrict__ bias,
                                                       void* __restrict__ outv,
                                                       int M) {
    constexpr int KSL = Dk / 32;     // 16x16x32 k-slices per step
    constexpr int VPL = 8;           // bf16 per lane (16 B) — always one uint4
    constexpr int NGR = 512 / GW;    // groups per block
    constexpr int RPG = 32 / NGR;    // rows per group (1 or 2)
    static_assert(GW * VPL == Dk, "group covers one row");
    __shared__ ushort As[32 * Dk];
    const int tid = threadIdx.x;
    const int l = tid & 63;
    const int wu = __builtin_amdgcn_readfirstlane(tid >> 6);  // 0..7
    const int wc = wu * (NJ * 16);
    const int row0 = blockIdx.x * 32;
    const int g = tid / GW;          // group id
    const int li = tid % GW;         // lane-in-group

    const ushort* Xli = X + li * VPL;   // per-lane column base

    f32x4 acc[2][NJ];
#pragma unroll
    for (int i = 0; i < 2; ++i)
#pragma unroll
        for (int j = 0; j < NJ; ++j)
            acc[i][j] = (f32x4){0.f, 0.f, 0.f, 0.f};

#pragma unroll 1
    for (int s = 0; s < 9; ++s) {
        // ---------- produce A tile in LDS ----------
#pragma unroll
        for (int b = 0; b < RPG; ++b) {
            const int lrow = g * RPG + b;
            const int node = row0 + lrow;
            const uint sw = ((uint)(lrow & 7)) << 4;
            const uint wbase = (uint)(lrow * (Dk * 2) + li * (VPL * 2));
            if (s < 8) {
                int c = 0; const int* sp = srcs;
                if (node < M) {
                    const int seg = node * RELS + s;
                    c = cnt[seg];
                    sp = srcs + (ends[seg] - c);
                }
                f32x2 ar[4];
#pragma unroll
                for (int p = 0; p < 4; ++p) ar[p] = (f32x2){0.f, 0.f};
                for (int i = 0; __any(i < c); i += 2) {
                    if (i < c) {
                        uint4 v0 = *(const uint4*)(Xli + (uint)sp[i] * (uint)Dk);
#pragma unroll
                        for (int p = 0; p < 4; ++p) {
                            uint u = (&v0.x)[p];
                            f32x2 t; t.x = __uint_as_float(u << 16); t.y = __uint_as_float(u & 0xffff0000u);
                            ar[p] += t;
                        }
                    }
                    if (i + 1 < c) {
                        uint4 v0 = *(const uint4*)(Xli + (uint)sp[i + 1] * (uint)Dk);
#pragma unroll
                        for (int p = 0; p < 4; ++p) {
                            uint u = (&v0.x)[p];
                            f32x2 t; t.x = __uint_as_float(u << 16); t.y = __uint_as_float(u & 0xffff0000u);
                            ar[p] += t;
                        }
                    }
                }
                if (node < M) {
                    const float scv = 1.f / fmaxf((float)c, 1.f);
                    short8 p0;
#pragma unroll
                    for (int e = 0; e < 8; ++e)
                        p0[e] = (short)f2bf(ar[e >> 1][e & 1] * scv);
                    *(short8*)((char*)As + (wbase ^ sw)) = p0;
                }
            } else {
                // root step: copy X rows (no mean)
                if (node < M)
                    *(short8*)((char*)As + (wbase ^ sw)) =
                        *(const short8*)(Xli + (uint)node * (uint)Dk);
            }
        }
        __syncthreads();
        // ---------- MFMA against Bp (direct from L2) ----------
        const int kb0 = s * KSL;
#pragma unroll
        for (int kk = 0; kk < KSL; ++kk) {
            short8 afr[2];
#pragma unroll
            for (int i = 0; i < 2; ++i) {
                const int r = i * 16 + (l & 15);
                const uint byte = ((uint)(r * (Dk * 2) + kk * 64 + ((l >> 4) * 16)))
                                  ^ (((uint)(r & 7)) << 4);
                afr[i] = *(const short8*)((const char*)As + byte);
            }
            short8 bfr[NJ];
#pragma unroll
            for (int j = 0; j < NJ; ++j) {
                const int cidx = wc + j * 16 + (l & 15);
                bfr[j] = *(const short8*)(Bp + ((long long)(kb0 + kk) * CO + cidx) * 32 + (l >> 4) * 8);
            }
#pragma unroll
            for (int i = 0; i < 2; ++i)
#pragma unroll
                for (int j = 0; j < NJ; ++j)
                    acc[i][j] = __builtin_amdgcn_mfma_f32_16x16x32_bf16(afr[i], bfr[j], acc[i][j], 0, 0, 0);
        }
        __syncthreads();
    }

    // ---------- epilogue: C/D map col=lane&15, row=(lane>>4)*4+q ----------
    float bj[NJ];
#pragma unroll
    for (int j = 0; j < NJ; ++j) bj[j] = bias[wc + j * 16 + (l & 15)];
#pragma unroll
    for (int i = 0; i < 2; ++i) {
#pragma unroll
        for (int q = 0; q < 4; ++q) {
            const int row = row0 + i * 16 + (l >> 4) * 4 + q;
            if (row >= M) continue;
#pragma unroll
            for (int j = 0; j < NJ; ++j) {
                const int col = wc + j * 16 + (l & 15);
                float v = acc[i][j][q] + bj[j];
                if (RELU) v = fmaxf(v, 0.0f);
                if (OUTBF) ((ushort*)outv)[(long long)row * CO + col] = f2bf(v);
                else       ((float*)outv)[(long long)row * CO + col] = v;
            }
        }
    }
}

// ================= launcher =================
extern "C" void kernel_launch(void* const* d_in, const int* in_sizes, int n_in,
                              void* d_out, int out_size, void* d_ws, size_t ws_size,
                              hipStream_t stream) {
    const float* x     = (const float*)d_in[0];
    const int*   ei    = (const int*)d_in[1];
    const int*   et    = (const int*)d_in[2];
    const float* W1    = (const float*)d_in[3];
    const float* root1 = (const float*)d_in[4];
    const float* b1    = (const float*)d_in[5];
    const float* W2    = (const float*)d_in[6];
    const float* root2 = (const float*)d_in[7];
    const float* b2    = (const float*)d_in[8];

    const int N = in_sizes[0] / 128;
    const int E = in_sizes[2];
    const int* src = ei;
    const int* dst = ei + E;
    const int NR = N * RELS;

    // workspace (bf16): h1b[N*256] | xb[N*128] | Bp1[1152*256] | Bp2[2304*128]
    // then ints: cnt[NR] | offs[NR] | srcs[E] | bsum[4096]
    ushort* h1b = (ushort*)d_ws;
    ushort* xb  = h1b + (size_t)N * 256;
    ushort* Bp1 = xb + (size_t)N * 128;
    ushort* Bp2 = Bp1 + (size_t)1152 * 256;
    int* cnt  = (int*)(Bp2 + (size_t)2304 * 128);
    int* offs = cnt + NR;
    int* srcs = offs + NR;
    int* bsum = srcs + E;
    size_t need = ((size_t)N * 384 + 589824) * 2 + ((size_t)2 * NR + E + 4096) * 4;
    if (need > ws_size) return;

    // ---- dtype prep ----
    {
        long long n4 = (long long)N * 128;
        cvt_bf16_k<<<(int)((n4 / 4 + 255) / 256), 256, 0, stream>>>(x, xb, n4);
    }
    makeBp_k<<<(1152 * 256 + 255) / 256, 256, 0, stream>>>(W1, root1, Bp1, 256, 1024, 128);
    makeBp_k<<<(2304 * 128 + 255) / 256, 256, 0, stream>>>(W2, root2, Bp2, 128, 2048, 256);

    // ---- CSR build ----
    hipMemsetAsync(cnt, 0, (size_t)NR * sizeof(int), stream);
    count_k<<<(E + 255) / 256, 256, 0, stream>>>(dst, et, cnt, E);
    const int nb1 = (NR + 2047) / 2048;
    scan1_k<<<nb1, 256, 0, stream>>>(cnt, offs, bsum, NR);
    scan2_k<<<1, 256, 0, stream>>>(bsum, nb1);
    scan3_k<<<nb1, 256, 0, stream>>>(offs, bsum, NR);
    fill_k<<<(E + 255) / 256, 256, 0, stream>>>(dst, et, src, offs, srcs, E);
    // offs now holds segment ENDS; start = end - cnt

    const int nblk = (N + 31) / 32;

    // ---- layer 1: h1b = relu([mean_r(x)|x] @ [W1;root1] + b1), bf16 out ----
    fused_rgcn_k<128, 16, 2, 256, true, true><<<nblk, 512, 0, stream>>>(
        xb, srcs, cnt, offs, Bp1, b1, h1b, N);

    // ---- layer 2: out = [mean_r(h1)|h1] @ [W2;root2] + b2, fp32 out ----
    fused_rgcn_k<256, 32, 1, 128, false, false><<<nblk, 512, 0, stream>>>(
        h1b, srcs, cnt, offs, Bp2, b2, d_out, N);
}